// Round 7
// baseline (669.051 us; speedup 1.0000x reference)
//
#include <hip/hip_runtime.h>

// CylinderFeatureEncoder R6 (resubmit; round 6 was an acquisition timeout):
// counting-sort by voxel + voxel-driven gather-max.
// Kills global atomicMax storm, out-init, and decode pass (R5: ~650MB RMW @2TB/s).
// MLP pipeline (split-bf16 hi/lo 3-term MFMA) unchanged from verified R5.

using bf16x8 = __attribute__((ext_vector_type(8))) short;
using f32x4  = __attribute__((ext_vector_type(4))) float;

constexpr int Bc = 2, Nc = 250000, Pc = 500000, Gc = 64, NSc = 524288;
constexpr float EPSV = 1e-5f;

// d_ws layout (bytes). Total ~12.1 MB.
constexpr int CB_OFF    = 0;          // f32[512] folded biases
constexpr int WSU_OFF   = 2048;       // u16 weight planes (~232 KB)
constexpr size_t SEGS_OFF  = 0x40000;   // u32[Pc]    voxel id per point (2.0 MB)
constexpr size_t CNT_OFF   = 0x280000;  // u32[NSc]   histogram (2 MB, memset 0)
constexpr size_t OFFA_OFF  = 0x500000;  // u32[NSc+1] exclusive offsets (+sentinel)
constexpr size_t CUR_OFF   = 0x740000;  // u32[NSc]   scatter cursors
constexpr size_t ORDER_OFF = 0x980000;  // u32[Pc]    point ids sorted by voxel
constexpr size_t BSUM_OFF  = 0xB80000;  // u32[512]   scan block sums
// weight-plane element offsets within wsu (u16 elems)
constexpr int W0E = 0;       // 4 frag-pairs  (A-layout, K padded 3->32)
constexpr int W1E = 4096;    // 16 frag-pairs (A-layout)
constexpr int W2E = 20480;   // 64 frag-pairs (A-layout)
constexpr int W3E = 86016;   // 32 frag-pairs (B-layout)

#define MFMA __builtin_amdgcn_mfma_f32_16x16x32_bf16

__device__ __forceinline__ bf16x8 mk8(unsigned a, unsigned b, unsigned c, unsigned d) {
  union { unsigned u[4]; bf16x8 v; } x;
  x.u[0] = a; x.u[1] = b; x.u[2] = c; x.u[3] = d;
  return x.v;
}

// ordered-u32 float encoding: monotone, 0u below all real encodings (= "empty")
__device__ __forceinline__ unsigned fenc(float f) {
  unsigned b = __float_as_uint(f);
  return (b & 0x80000000u) ? ~b : (b | 0x80000000u);
}
__device__ __forceinline__ unsigned fdec(unsigned u) {
  if (u == 0u) return 0u;
  return (u & 0x80000000u) ? (u & 0x7fffffffu) : ~u;
}

// ---- K1: weight prep (blocks 0..233) + histogram/segs (blocks 234+) ----
__global__ void prep_hist_kernel(
    const float* __restrict__ G0, const float* __restrict__ B0, const float* __restrict__ M0, const float* __restrict__ V0,
    const float* __restrict__ G1, const float* __restrict__ B1, const float* __restrict__ M1, const float* __restrict__ V1,
    const float* __restrict__ G2, const float* __restrict__ B2, const float* __restrict__ M2, const float* __restrict__ V2,
    const float* __restrict__ G3, const float* __restrict__ B3, const float* __restrict__ M3, const float* __restrict__ V3,
    const float* __restrict__ W0, const float* __restrict__ bb0,
    const float* __restrict__ W1, const float* __restrict__ bb1,
    const float* __restrict__ W2, const float* __restrict__ bb2,
    const float* __restrict__ W3, const float* __restrict__ bb3,
    const int* __restrict__ pt_ind,
    float* __restrict__ cb, unsigned short* __restrict__ wsu,
    unsigned* __restrict__ segs, unsigned* __restrict__ cnt)
{
  if (blockIdx.x >= 234) {
    const int p = (blockIdx.x - 234) * 256 + threadIdx.x;
    if (p < Pc) {
      const int ix = pt_ind[p * 3], iy = pt_ind[p * 3 + 1], iz = pt_ind[p * 3 + 2];
      const int b = (p >= Nc) ? 1 : 0;
      const unsigned seg = ((unsigned)(b * Gc + iz) * Gc + iy) * Gc + ix;
      segs[p] = seg;
      atomicAdd(&cnt[seg], 1u);
    }
    return;
  }
  const int i = blockIdx.x * 256 + threadIdx.x;
  if (i < 59392) {
    const int u = i >> 9, pos = i & 511;
    const int lane = pos >> 3, j = pos & 7;
    const int row16 = lane & 15, kin = (lane >> 4) * 8 + j;
    float v; int dstbase;
    if (u < 4) {
      const int mt = u, fo = mt * 16 + row16, k = kin;
      const float t1 = G1[fo] * rsqrtf(V1[fo] + EPSV);
      v = (k < 3) ? (G0[k] * rsqrtf(V0[k] + EPSV)) * W0[k * 64 + fo] * t1 : 0.f;
      dstbase = W0E + u * 1024;
    } else if (u < 20) {
      const int q = u - 4, mt = q >> 1, kt = q & 1;
      const int fo = mt * 16 + row16, k = kt * 32 + kin;
      v = W1[k * 128 + fo] * (G2[fo] * rsqrtf(V2[fo] + EPSV));
      dstbase = W1E + q * 1024;
    } else if (u < 84) {
      const int q = u - 20, mt = q >> 2, kt = q & 3;
      const int fo = mt * 16 + row16, k = kt * 32 + kin;
      v = W2[k * 256 + fo] * (G3[fo] * rsqrtf(V3[fo] + EPSV));
      dstbase = W2E + q * 1024;
    } else {
      const int q = u - 84, kt = q >> 2, nt = q & 3;
      const int k = kt * 32 + kin, fo = nt * 16 + row16;
      v = W3[k * 64 + fo];
      dstbase = W3E + q * 1024;
    }
    const unsigned uh = __float_as_uint(v) & 0xffff0000u;
    const float lo = v - __uint_as_float(uh);
    wsu[dstbase + pos]       = (unsigned short)(uh >> 16);
    wsu[dstbase + 512 + pos] = (unsigned short)(__float_as_uint(lo) >> 16);
  } else if (i < 59904) {
    const int f = i - 59392;
    if (f < 64) {
      const int fo = f;
      const float t1 = G1[fo] * rsqrtf(V1[fo] + EPSV);
      float s = 0.f;
      for (int c = 0; c < 3; ++c) {
        const float t0 = G0[c] * rsqrtf(V0[c] + EPSV);
        s += (B0[c] - M0[c] * t0) * W0[c * 64 + fo];
      }
      cb[fo] = (bb0[fo] + s - M1[fo]) * t1 + B1[fo];
    } else if (f < 192) {
      const int fo = f - 64;
      const float t2 = G2[fo] * rsqrtf(V2[fo] + EPSV);
      cb[64 + fo] = (bb1[fo] - M2[fo]) * t2 + B2[fo];
    } else if (f < 448) {
      const int fo = f - 192;
      const float t3 = G3[fo] * rsqrtf(V3[fo] + EPSV);
      cb[192 + fo] = (bb2[fo] - M3[fo]) * t3 + B3[fo];
    } else {
      const int fo = f - 448;
      cb[448 + fo] = bb3[fo];
    }
  }
}

// ---- K2: scan level 1 — 512 blocks x 1024 elems -> exclusive local, bsum ----
__global__ void scan1_kernel(const unsigned* __restrict__ cnt,
                             unsigned* __restrict__ offa, unsigned* __restrict__ bsum) {
  __shared__ unsigned wsum[4];
  const int b = blockIdx.x, t = threadIdx.x;
  const uint4 v = ((const uint4*)cnt)[b * 256 + t];
  const unsigned s0 = v.x, s01 = v.x + v.y, s012 = s01 + v.z, s = s012 + v.w;
  int sc = (int)s;
  #pragma unroll
  for (int d = 1; d < 64; d <<= 1) {
    int o = __shfl_up(sc, d);
    if ((t & 63) >= d) sc += o;
  }
  if ((t & 63) == 63) wsum[t >> 6] = (unsigned)sc;
  __syncthreads();
  unsigned wbase = 0;
  for (int w = 0; w < (t >> 6); ++w) wbase += wsum[w];
  const unsigned excl = wbase + (unsigned)sc - s;
  ((uint4*)offa)[b * 256 + t] = make_uint4(excl, excl + s0, excl + s01, excl + s012);
  if (t == 255) bsum[b] = wbase + (unsigned)sc;
}

// ---- K3: scan level 2 — exclusive scan of bsum[512] in-place ----
__global__ void scan2_kernel(unsigned* __restrict__ bsum) {
  __shared__ unsigned wsum[8];
  const int t = threadIdx.x;
  const unsigned s = bsum[t];
  int sc = (int)s;
  #pragma unroll
  for (int d = 1; d < 64; d <<= 1) {
    int o = __shfl_up(sc, d);
    if ((t & 63) >= d) sc += o;
  }
  if ((t & 63) == 63) wsum[t >> 6] = (unsigned)sc;
  __syncthreads();
  unsigned wbase = 0;
  for (int w = 0; w < (t >> 6); ++w) wbase += wsum[w];
  bsum[t] = wbase + (unsigned)sc - s;
}

// ---- K4: scan level 3 — add block bases; produce offa (final) and cur copy ----
__global__ void scan3_kernel(unsigned* __restrict__ offa, unsigned* __restrict__ cur,
                             const unsigned* __restrict__ bsum) {
  const int b = blockIdx.x, t = threadIdx.x;
  uint4 v = ((uint4*)offa)[b * 256 + t];
  const unsigned a = bsum[b];
  v.x += a; v.y += a; v.z += a; v.w += a;
  ((uint4*)offa)[b * 256 + t] = v;
  ((uint4*)cur)[b * 256 + t] = v;
  if (b == 0 && t == 0) offa[NSc] = (unsigned)Pc;  // sentinel
}

// ---- K5: scatter sorted point ids ----
__global__ void scatter_kernel(const unsigned* __restrict__ segs,
                               unsigned* __restrict__ cur, unsigned* __restrict__ order) {
  const int p = blockIdx.x * 256 + threadIdx.x;
  if (p < Pc) {
    const unsigned pos = atomicAdd(&cur[segs[p]], 1u);
    order[pos] = p;
  }
}

// ---- epilogue helpers (verified R2/R5) ----
struct PKp { unsigned h0, h1, l0, l1; };

__device__ __forceinline__ PKp epi_relu(f32x4 d) {
  const float e0 = fmaxf(d[0], 0.f), e1 = fmaxf(d[1], 0.f);
  const float e2 = fmaxf(d[2], 0.f), e3 = fmaxf(d[3], 0.f);
  const unsigned u0 = __float_as_uint(e0) & 0xffff0000u, u1 = __float_as_uint(e1) & 0xffff0000u;
  const unsigned u2 = __float_as_uint(e2) & 0xffff0000u, u3 = __float_as_uint(e3) & 0xffff0000u;
  PKp r;
  r.h0 = (u0 >> 16) | u1;
  r.h1 = (u2 >> 16) | u3;
  const float f0 = e0 - __uint_as_float(u0), f1 = e1 - __uint_as_float(u1);
  const float f2 = e2 - __uint_as_float(u2), f3 = e3 - __uint_as_float(u3);
  r.l0 = (__float_as_uint(f0) >> 16) | (__float_as_uint(f1) & 0xffff0000u);
  r.l1 = (__float_as_uint(f2) >> 16) | (__float_as_uint(f3) & 0xffff0000u);
  return r;
}

__device__ __forceinline__ void trans2(const PKp& A, const PKp& B, int lane,
                                       bf16x8& fh, bf16x8& fl) {
  const int idx0 = ((lane & 15) << 2) | (((lane >> 4) & 1) << 7);
  const int idx1 = idx0 + 64;
  const bool hi = lane >= 32;
  unsigned v0, v1, v2, v3;
  { unsigned a = __builtin_amdgcn_ds_bpermute(idx0, (int)A.h0), b = __builtin_amdgcn_ds_bpermute(idx0, (int)B.h0); v0 = hi ? b : a; }
  { unsigned a = __builtin_amdgcn_ds_bpermute(idx0, (int)A.h1), b = __builtin_amdgcn_ds_bpermute(idx0, (int)B.h1); v1 = hi ? b : a; }
  { unsigned a = __builtin_amdgcn_ds_bpermute(idx1, (int)A.h0), b = __builtin_amdgcn_ds_bpermute(idx1, (int)B.h0); v2 = hi ? b : a; }
  { unsigned a = __builtin_amdgcn_ds_bpermute(idx1, (int)A.h1), b = __builtin_amdgcn_ds_bpermute(idx1, (int)B.h1); v3 = hi ? b : a; }
  fh = mk8(v0, v1, v2, v3);
  { unsigned a = __builtin_amdgcn_ds_bpermute(idx0, (int)A.l0), b = __builtin_amdgcn_ds_bpermute(idx0, (int)B.l0); v0 = hi ? b : a; }
  { unsigned a = __builtin_amdgcn_ds_bpermute(idx0, (int)A.l1), b = __builtin_amdgcn_ds_bpermute(idx0, (int)B.l1); v1 = hi ? b : a; }
  { unsigned a = __builtin_amdgcn_ds_bpermute(idx1, (int)A.l0), b = __builtin_amdgcn_ds_bpermute(idx1, (int)B.l0); v2 = hi ? b : a; }
  { unsigned a = __builtin_amdgcn_ds_bpermute(idx1, (int)A.l1), b = __builtin_amdgcn_ds_bpermute(idx1, (int)B.l1); v3 = hi ? b : a; }
  fl = mk8(v0, v1, v2, v3);
}

// ---- K6: voxel-driven MLP + max-gather. Wave owns 64 voxels; no barriers. ----
__global__ __launch_bounds__(256, 2)
void mlp_gather(const float* __restrict__ pt_fea,
                const unsigned* __restrict__ order, const unsigned* __restrict__ segs,
                const unsigned* __restrict__ offa,
                const unsigned short* __restrict__ wsu, const float* __restrict__ cb,
                float* __restrict__ out)
{
  __shared__ unsigned accum[4][64 * 65];       // 4 waves x 16.6 KB, ordered-u32 max
  __shared__ unsigned char vls[4][192];        // slot -> voxel-local id (255 = pad)

  const int tid = threadIdx.x, lane = tid & 63, wv = tid >> 6;
  const int g = lane >> 4, c16 = lane & 15;
  const unsigned chunk = blockIdx.x * 4 + wv;  // 8192 chunks of 64 voxels
  const unsigned vbase = chunk << 6;
  const unsigned base = offa[vbase], end = offa[vbase + 64];
  const int n = (int)(end - base);

  for (int i = lane; i < 64 * 65; i += 64) accum[wv][i] = 0u;

  float c3v[4];
  #pragma unroll
  for (int n3 = 0; n3 < 4; ++n3) c3v[n3] = cb[448 + n3 * 16 + c16];

  const int ntile = min((n + 31) >> 5, 6);
  for (int t = 0; t < ntile; ++t) {
    // ---- gather B0 frags + fill vl table ----
    bf16x8 b0h[2], b0l[2];
    #pragma unroll
    for (int nt = 0; nt < 2; ++nt) {
      const int slot = t * 32 + nt * 16 + c16;
      const bool valid = slot < n;
      float x = 0.f, y = 0.f, z = 0.f;
      unsigned char vl = 255;
      if (valid) {
        const unsigned pid = order[base + slot];
        const float* pp = pt_fea + (size_t)pid * 3;
        x = pp[0]; y = pp[1]; z = pp[2];
        vl = (unsigned char)(segs[pid] - vbase);
      }
      vls[wv][slot] = vl;   // 4 g-lanes write identical value
      const unsigned ux = __float_as_uint(x) & 0xffff0000u;
      const unsigned uy = __float_as_uint(y) & 0xffff0000u;
      const unsigned uz = __float_as_uint(z) & 0xffff0000u;
      const float lx = x - __uint_as_float(ux), ly = y - __uint_as_float(uy), lz = z - __uint_as_float(uz);
      const unsigned ph0 = (ux >> 16) | uy, ph1 = (uz >> 16);
      const unsigned pl0 = (__float_as_uint(lx) >> 16) | (__float_as_uint(ly) & 0xffff0000u);
      const unsigned pl1 = (__float_as_uint(lz) >> 16);
      const bool g0ok = (g == 0);
      b0h[nt] = mk8(g0ok ? ph0 : 0u, g0ok ? ph1 : 0u, 0u, 0u);
      b0l[nt] = mk8(g0ok ? pl0 : 0u, g0ok ? pl1 : 0u, 0u, 0u);
    }

    // ---- L0 (3->64) ----
    bf16x8 B1h[2][2], B1l[2][2];
    #pragma unroll
    for (int K = 0; K < 2; ++K) {
      PKp pk[2][2];
      #pragma unroll
      for (int e = 0; e < 2; ++e) {
        const int mt = 2 * K + e;
        const bf16x8 wh = *(const bf16x8*)(wsu + W0E + mt * 1024 + lane * 8);
        const bf16x8 wl = *(const bf16x8*)(wsu + W0E + mt * 1024 + 512 + lane * 8);
        const f32x4 cbv = *(const f32x4*)(cb + mt * 16 + g * 4);
        #pragma unroll
        for (int nt = 0; nt < 2; ++nt) {
          f32x4 acc = cbv;
          acc = MFMA(wh, b0h[nt], acc, 0, 0, 0);
          acc = MFMA(wh, b0l[nt], acc, 0, 0, 0);
          acc = MFMA(wl, b0h[nt], acc, 0, 0, 0);
          pk[e][nt] = epi_relu(acc);
        }
      }
      #pragma unroll
      for (int nt = 0; nt < 2; ++nt) trans2(pk[0][nt], pk[1][nt], lane, B1h[K][nt], B1l[K][nt]);
    }

    // ---- L1 (64->128) ----
    bf16x8 B2h[4][2], B2l[4][2];
    #pragma unroll
    for (int K = 0; K < 4; ++K) {
      PKp pk[2][2];
      #pragma unroll
      for (int e = 0; e < 2; ++e) {
        const int mt = 2 * K + e;
        bf16x8 w[2][2];
        #pragma unroll
        for (int kt = 0; kt < 2; ++kt) {
          const unsigned short* wp = wsu + W1E + (mt * 2 + kt) * 1024 + lane * 8;
          w[kt][0] = *(const bf16x8*)wp;
          w[kt][1] = *(const bf16x8*)(wp + 512);
        }
        const f32x4 cbv = *(const f32x4*)(cb + 64 + mt * 16 + g * 4);
        #pragma unroll
        for (int nt = 0; nt < 2; ++nt) {
          f32x4 acc = cbv;
          #pragma unroll
          for (int kt = 0; kt < 2; ++kt) {
            acc = MFMA(w[kt][0], B1h[kt][nt], acc, 0, 0, 0);
            acc = MFMA(w[kt][0], B1l[kt][nt], acc, 0, 0, 0);
            acc = MFMA(w[kt][1], B1h[kt][nt], acc, 0, 0, 0);
          }
          pk[e][nt] = epi_relu(acc);
        }
      }
      #pragma unroll
      for (int nt = 0; nt < 2; ++nt) trans2(pk[0][nt], pk[1][nt], lane, B2h[K][nt], B2l[K][nt]);
    }

    // ---- L2 (128->256) fused with L3 (256->64) ----
    f32x4 acc3[2][4];
    #pragma unroll
    for (int pm = 0; pm < 2; ++pm)
      #pragma unroll
      for (int n3 = 0; n3 < 4; ++n3)
        acc3[pm][n3] = (f32x4){c3v[n3], c3v[n3], c3v[n3], c3v[n3]};

    #pragma unroll 1
    for (int K = 0; K < 8; ++K) {
      PKp pk[2][2];
      #pragma unroll
      for (int e = 0; e < 2; ++e) {
        const int mt = 2 * K + e;
        bf16x8 w[4][2];
        #pragma unroll
        for (int kt = 0; kt < 4; ++kt) {
          const unsigned short* wp = wsu + W2E + (mt * 4 + kt) * 1024 + lane * 8;
          w[kt][0] = *(const bf16x8*)wp;
          w[kt][1] = *(const bf16x8*)(wp + 512);
        }
        const f32x4 cbv = *(const f32x4*)(cb + 192 + mt * 16 + g * 4);
        #pragma unroll
        for (int nt = 0; nt < 2; ++nt) {
          f32x4 acc = cbv;
          #pragma unroll
          for (int kt = 0; kt < 4; ++kt) {
            acc = MFMA(w[kt][0], B2h[kt][nt], acc, 0, 0, 0);
            acc = MFMA(w[kt][0], B2l[kt][nt], acc, 0, 0, 0);
            acc = MFMA(w[kt][1], B2h[kt][nt], acc, 0, 0, 0);
          }
          pk[e][nt] = epi_relu(acc);
        }
      }
      bf16x8 w3[4][2];
      #pragma unroll
      for (int n3 = 0; n3 < 4; ++n3) {
        w3[n3][0] = *(const bf16x8*)(wsu + W3E + (K * 4 + n3) * 1024 + lane * 8);
        w3[n3][1] = *(const bf16x8*)(wsu + W3E + (K * 4 + n3) * 1024 + 512 + lane * 8);
      }
      #pragma unroll
      for (int nt = 0; nt < 2; ++nt) {
        bf16x8 a3h, a3l;
        trans2(pk[0][nt], pk[1][nt], lane, a3h, a3l);
        #pragma unroll
        for (int n3 = 0; n3 < 4; ++n3) {
          acc3[nt][n3] = MFMA(a3h, w3[n3][0], acc3[nt][n3], 0, 0, 0);
          acc3[nt][n3] = MFMA(a3l, w3[n3][0], acc3[nt][n3], 0, 0, 0);
          acc3[nt][n3] = MFMA(a3h, w3[n3][1], acc3[nt][n3], 0, 0, 0);
        }
      }
    }

    // ---- merge tile into per-wave voxel accumulator (LDS atomic max) ----
    #pragma unroll
    for (int pm = 0; pm < 2; ++pm) {
      #pragma unroll
      for (int j = 0; j < 4; ++j) {
        const int slot = t * 32 + pm * 16 + g * 4 + j;
        const int vl = vls[wv][slot];
        if (vl < 64) {
          #pragma unroll
          for (int n3 = 0; n3 < 4; ++n3) {
            atomicMax(&accum[wv][vl * 65 + c16 + 16 * n3], fenc(acc3[pm][n3][j]));
          }
        }
      }
    }
  }

  // ---- store 64 voxel rows exactly once (coalesced); 0u decodes to 0.0 ----
  for (int r = 0; r < 64; ++r) {
    const unsigned e = accum[wv][r * 65 + lane];
    out[(size_t)(vbase + r) * 64 + lane] = __uint_as_float(fdec(e));
  }
}

extern "C" void kernel_launch(void* const* d_in, const int* in_sizes, int n_in,
                              void* d_out, int out_size, void* d_ws, size_t ws_size,
                              hipStream_t stream) {
  const float* pt_fea = (const float*)d_in[0];
  const int*   pt_ind = (const int*)d_in[1];

  char* ws = (char*)d_ws;
  float*          cb    = (float*)(ws + CB_OFF);
  unsigned short* wsu   = (unsigned short*)(ws + WSU_OFF);
  unsigned*       segs  = (unsigned*)(ws + SEGS_OFF);
  unsigned*       cnt   = (unsigned*)(ws + CNT_OFF);
  unsigned*       offa  = (unsigned*)(ws + OFFA_OFF);
  unsigned*       cur   = (unsigned*)(ws + CUR_OFF);
  unsigned*       order = (unsigned*)(ws + ORDER_OFF);
  unsigned*       bsum  = (unsigned*)(ws + BSUM_OFF);

  hipMemsetAsync(cnt, 0, (size_t)NSc * 4, stream);

  hipLaunchKernelGGL(prep_hist_kernel, dim3(234 + 1954), dim3(256), 0, stream,
                     (const float*)d_in[2],  (const float*)d_in[3],  (const float*)d_in[4],  (const float*)d_in[5],
                     (const float*)d_in[6],  (const float*)d_in[7],  (const float*)d_in[8],  (const float*)d_in[9],
                     (const float*)d_in[10], (const float*)d_in[11], (const float*)d_in[12], (const float*)d_in[13],
                     (const float*)d_in[14], (const float*)d_in[15], (const float*)d_in[16], (const float*)d_in[17],
                     (const float*)d_in[18], (const float*)d_in[19], (const float*)d_in[20], (const float*)d_in[21],
                     (const float*)d_in[22], (const float*)d_in[23], (const float*)d_in[24], (const float*)d_in[25],
                     pt_ind, cb, wsu, segs, cnt);

  hipLaunchKernelGGL(scan1_kernel, dim3(512), dim3(256), 0, stream, cnt, offa, bsum);
  hipLaunchKernelGGL(scan2_kernel, dim3(1), dim3(512), 0, stream, bsum);
  hipLaunchKernelGGL(scan3_kernel, dim3(512), dim3(256), 0, stream, offa, cur, bsum);
  hipLaunchKernelGGL(scatter_kernel, dim3(1954), dim3(256), 0, stream, segs, cur, order);

  hipLaunchKernelGGL(mlp_gather, dim3(2048), dim3(256), 0, stream,
                     pt_fea, order, segs, offa, wsu, cb, (float*)d_out);
}